// Round 14
// baseline (229.360 us; speedup 1.0000x reference)
//
#include <hip/hip_runtime.h>
#include <cmath>

#define EPSF 1e-5f
typedef unsigned int  uint32;
typedef unsigned short u16;
typedef __attribute__((ext_vector_type(8))) short bfrag;    // 8 bf16 = 4 VGPRs
typedef __attribute__((ext_vector_type(4))) float f32x4;
typedef __attribute__((ext_vector_type(16))) float f32x16;

constexpr int Qn   = 16384;
constexpr int KS   = 168;    // fhat K stride (bf16) = 336 B
constexpr int PXS  = 42;     // px stride (u16)
constexpr int AGS  = 168;    // agg row stride (u16)
constexpr int Nd   = 4096;
constexpr float LOG2E = 1.4426950408889634f;

constexpr int OFF_W1  = 0;                 // W_fc1 16x16 tiles (unused by stage1 now, kept)
constexpr int OFF_WM1 = 23040;             // W_mlp1 8x5x512
constexpr int OFF_W2  = 43520;             // W_fc2 16x16 tiles (used by fused stage2)
constexpr int OFF_WM2 = 66560;             // W_mlp2
constexpr int OFF_WLB = 87040;
constexpr int OFF_WSC = 87552;
constexpr int OFF_WCL = 90112;
constexpr int END_W   = 90624;
constexpr int BN_LB = 0;
constexpr int BN_SC = 20;
constexpr int BN_CL = 168;
constexpr int BN_M1 = 188;
constexpr int BN_M2 = 444;
constexpr int BN_TOT = 700;
constexpr int OFF_FT  = END_W + 2 * BN_TOT;                 // u16: 2Q x 128
constexpr int OFF_AG  = OFF_FT + 2 * Qn * 128;              // u16: 2Q x 168
constexpr int OFF_W32 = OFF_AG + 2 * Qn * AGS;              // u16: W_fc1/W_fc2 in 32x32 tiles
constexpr int N_W32   = 2 * 5 * 10 * 512;                   // 51200
constexpr int PREP_N  = END_W + BN_TOT;

__device__ __forceinline__ u16 f2b(float f) {
    uint32 u = __float_as_uint(f);
    uint32 r = (u + 0x7fffu + ((u >> 16) & 1u)) >> 16;
    return (u16)r;
}
__device__ __forceinline__ float b2f(u16 h) {
    return __uint_as_float(((uint32)h) << 16);
}
__device__ __forceinline__ uint32 cvtpk(float a, float b) {
    uint32 r;
    asm("v_cvt_pk_bf16_f32 %0, %1, %2" : "=v"(r) : "v"(a), "v"(b));
    return r;
}
__device__ __forceinline__ u16 cvt1(float a) { return (u16)cvtpk(a, a); }
__device__ __forceinline__ float exp2_hw(float x) { return __builtin_amdgcn_exp2f(x); }

// ---------------- prep: 16x16 tiles + conv weights + BN pairs ----------------
__global__ __launch_bounds__(256) void prep_weights(
    const float* __restrict__ Wfc1, const float* __restrict__ Wmlp1,
    const float* __restrict__ Wfc2, const float* __restrict__ Wmlp2,
    const float* __restrict__ Wlb,  const float* __restrict__ Wsc,
    const float* __restrict__ Wcl,
    const float* __restrict__ g_lb, const float* __restrict__ b_lb,
    const float* __restrict__ m_lb, const float* __restrict__ v_lb,
    const float* __restrict__ g_sc, const float* __restrict__ b_sc,
    const float* __restrict__ m_sc, const float* __restrict__ v_sc,
    const float* __restrict__ g_cl, const float* __restrict__ b_cl,
    const float* __restrict__ m_cl, const float* __restrict__ v_cl,
    const float* __restrict__ g1, const float* __restrict__ b1,
    const float* __restrict__ m1, const float* __restrict__ v1,
    const float* __restrict__ g2, const float* __restrict__ b2,
    const float* __restrict__ m2, const float* __restrict__ v2,
    u16* __restrict__ ws16)
{
    int i = blockIdx.x * 256 + threadIdx.x;
    if (i >= PREP_N) return;
    if (i >= END_W) {                      // BN pairs
        int j = i - END_W;
        const float *g, *bb, *m, *v; int o2;
        if (j < BN_SC)      { g = g_lb; bb = b_lb; m = m_lb; v = v_lb; o2 = j - BN_LB; }
        else if (j < BN_CL) { g = g_sc; bb = b_sc; m = m_sc; v = v_sc; o2 = j - BN_SC; }
        else if (j < BN_M1) { g = g_cl; bb = b_cl; m = m_cl; v = v_cl; o2 = j - BN_CL; }
        else if (j < BN_M2) { g = g1;   bb = b1;   m = m1;   v = v1;   o2 = j - BN_M1; }
        else                { g = g2;   bb = b2;   m = m2;   v = v2;   o2 = j - BN_M2; }
        int o = o2 >> 1;
        float sc_ = g[o] * rsqrtf(v[o] + EPSF);
        ((float*)(ws16 + END_W))[j] = (o2 & 1) ? (bb[o] - m[o] * sc_) : sc_;
        return;
    }
    int lane = (i >> 3) & 63, jj = i & 7;
    int row16 = lane & 15;
    int kf = ((lane >> 4) << 3) + jj;
    float v = 0.f;
    if (i < OFF_WLB) {                    // att / mlp weights, K remapped
        const float* src; int nrows; int idx; bool fc = false;
        if (i < OFF_WM1)      { src = Wfc1;  nrows = 138; idx = i - OFF_W1;  fc = true; }
        else if (i < OFF_W2)  { src = Wmlp1; nrows = 128; idx = i - OFF_WM1; }
        else if (i < OFF_WM2) { src = Wfc2;  nrows = 138; idx = i - OFF_W2;  fc = true; }
        else                  { src = Wmlp2; nrows = 128; idx = i - OFF_WM2; }
        int t = idx >> 9, nt = t / 5, kt = t - nt * 5;
        int row = nt * 16 + row16;
        int kp  = kt * 32 + kf;
        int k   = (kp < 10) ? kp : kp - 2;
        if (row < nrows && kp < 140 && kp != 10 && kp != 11) {
            v = src[row * 138 + k];
            if (fc) v *= LOG2E;
        }
    } else {                              // conv weights, K = 10 (pad 32)
        const float* src; int nrows; int idx;
        if (i < OFF_WSC)      { src = Wlb; nrows = 10; idx = i - OFF_WLB; }
        else if (i < OFF_WCL) { src = Wsc; nrows = 74; idx = i - OFF_WSC; }
        else                  { src = Wcl; nrows = 10; idx = i - OFF_WCL; }
        int t = idx >> 9;
        int row = t * 16 + row16;
        if (row < nrows && kf < 10) v = src[row * 10 + kf];
    }
    ws16[i] = f2b(v);
}

// ---------------- prep: W_fc1 / W_fc2 in 32x32x16 fragment tiling ----------------
__global__ __launch_bounds__(256) void prep_weights32(
    const float* __restrict__ Wfc1, const float* __restrict__ Wfc2,
    u16* __restrict__ ws16)
{
    int i = blockIdx.x * 256 + threadIdx.x;
    if (i >= N_W32) return;
    const float* src = (i < N_W32 / 2) ? Wfc1 : Wfc2;
    int idx = (i < N_W32 / 2) ? i : i - N_W32 / 2;
    int t = idx >> 9;                     // 0..49 = nt*10 + kt
    int lane = (idx >> 3) & 63, j = idx & 7;
    int nt = t / 10, kt = t - nt * 10;
    int o  = nt * 32 + (lane & 31);       // output channel (B col)
    int kp = kt * 16 + ((lane >> 5) << 3) + j;
    int k  = (kp < 10) ? kp : kp - 2;
    float v = 0.f;
    if (o < 138 && kp < 140 && kp != 10 && kp != 11) v = src[o * 138 + k] * LOG2E;
    ws16[OFF_W32 + i] = f2b(v);
}

// ---- helpers ----
__device__ __forceinline__ void loadB(bfrag (&bf)[5], const u16* __restrict__ Wt,
                                      int nt, int lane) {
    #pragma unroll
    for (int kt = 0; kt < 5; ++kt)
        bf[kt] = *(const bfrag*)&Wt[((nt * 5 + kt) << 9) + (lane << 3)];
}
__device__ __forceinline__ void mfma16(const bfrag (&af)[5], const bfrag (&bf)[5],
                                       f32x4 &a0) {
    const f32x4 zf = {0.f, 0.f, 0.f, 0.f};
    a0 = zf;
    #pragma unroll
    for (int kt = 0; kt < 5; ++kt)
        a0 = __builtin_amdgcn_mfma_f32_16x16x32_bf16(af[kt], bf[kt], a0, 0, 0, 0);
}
__device__ __forceinline__ void soft16(
    const f32x4& a0, int nt,
    int lane, int lrow, const u16* __restrict__ fr0, u16* __restrict__ ag)
{
    const int ch  = nt * 16 + lrow;
    const int chp = ch + (ch >= 10 ? 2 : 0);
    float s = 0.f, num = 0.f;
    #pragma unroll
    for (int r = 0; r < 4; ++r) {
        float e = exp2_hw(a0[r]);
        s += e;
        num += e * b2f(fr0[r * KS + chp]);
    }
    s   += __shfl_xor(s, 16);   s   += __shfl_xor(s, 32);
    num += __shfl_xor(num, 16); num += __shfl_xor(num, 32);
    if (lane < 16)
        ag[chp] = cvt1((ch < 138) ? num * __builtin_amdgcn_rcpf(s) : 0.f);
}
#define SB() __builtin_amdgcn_sched_barrier(0)

// one 32-channel att unit via 32x32x16: 10 MFMAs + in-register softmax
__device__ __forceinline__ void unit32(
    int nt, const bfrag (&af32)[10], const u16* __restrict__ W32,
    int lane, const u16* __restrict__ frh, u16* __restrict__ ag)
{
    f32x16 acc;
    #pragma unroll
    for (int r = 0; r < 16; ++r) acc[r] = 0.f;
    #pragma unroll
    for (int kt = 0; kt < 10; ++kt) {
        bfrag bf = *(const bfrag*)&W32[((nt * 10 + kt) << 9) + (lane << 3)];
        acc = __builtin_amdgcn_mfma_f32_32x32x16_bf16(af32[kt], bf, acc, 0, 0, 0);
    }
    const int ch  = nt * 32 + (lane & 31);
    const int chp = ch + (ch >= 10 ? 2 : 0);
    float s = 0.f, num = 0.f;
    #pragma unroll
    for (int reg = 0; reg < 16; ++reg) {
        float e = exp2_hw(acc[reg]);
        s += e;
        const int brow = (reg & 3) + 8 * (reg >> 2);   // + 4*hi folded into frh
        num += e * b2f(frh[brow * KS + chp]);
    }
    s   += __shfl_xor(s, 32);
    num += __shfl_xor(num, 32);
    if (lane < 32)
        ag[chp] = cvt1((ch < 138) ? num * __builtin_amdgcn_rcpf(s) : 0.f);
}

// ---------------- Stage 1: 1 query/block, 2 waves, 32x32 att ----------------
__global__ __launch_bounds__(128, 8) void stage1(
    const float* __restrict__ feat_lb, const float* __restrict__ feat_sc,
    const int* __restrict__ nm_lb, const int* __restrict__ nm_sc,
    const float* __restrict__ c_lb, const float* __restrict__ c_sc,
    const float* __restrict__ c_q,
    u16* __restrict__ ws16)
{
    __shared__ __align__(16) u16 fhat[32 * KS];      // 10752 B
    __shared__ __align__(16) u16 pxs[32 * PXS];      // 2688 B

    const int tid  = threadIdx.x;
    const int bq   = blockIdx.x;
    const int b    = bq >> 14;
    const int lane = tid & 63;
    const int h    = tid >> 6;               // 0..1
    const int lrow = lane & 15;
    const int lgr  = lane >> 4;

    const u16* W32  = ws16 + OFF_W32;        // W_fc1 32x32 tiles
    const float* bn = (const float*)(ws16 + END_W);
    u16* ag = ws16 + OFF_AG + (size_t)bq * AGS;

    // ---- conv weights + BN for my subset ----
    bfrag wcv[3];
    float2 bnv[3];
    if (h == 0) {
        wcv[0] = *(const bfrag*)&ws16[OFF_WLB + (lane << 3)];
        wcv[1] = *(const bfrag*)&ws16[OFF_WSC + (lane << 3)];
        wcv[2] = *(const bfrag*)&ws16[OFF_WSC + 512 + (lane << 3)];
        bnv[0] = (lrow < 10) ? *(const float2*)&bn[BN_LB + lrow * 2] : float2{0.f, 0.f};
        bnv[1] = *(const float2*)&bn[BN_SC + lrow * 2];
        bnv[2] = *(const float2*)&bn[BN_SC + (16 + lrow) * 2];
    } else {
        #pragma unroll
        for (int t = 0; t < 3; ++t) {
            wcv[t] = *(const bfrag*)&ws16[OFF_WSC + ((2 + t) << 9) + (lane << 3)];
            int o = (2 + t) * 16 + lrow;
            bnv[t] = (o < 74) ? *(const float2*)&bn[BN_SC + o * 2] : float2{0.f, 0.f};
        }
    }

    // ---- staging: features -> fhat (bf16), zero pads, px ----
    {
        const float4* flb = (const float4*)(feat_lb + (size_t)bq * 2048);
        float4 r0[4];
        #pragma unroll
        for (int it = 0; it < 4; ++it) r0[it] = flb[tid + it * 128];
        const float4* fsc = (const float4*)(feat_sc + (size_t)bq * 1024);
        float4 r1[2];
        #pragma unroll
        for (int it = 0; it < 2; ++it) r1[it] = fsc[tid + it * 128];
        #pragma unroll
        for (int it = 0; it < 4; ++it) {
            int u = tid + it * 128;
            int nbr = u >> 5, c4 = u & 31;
            uint32* d = (uint32*)&fhat[nbr * KS + 12 + c4 * 4];
            d[0] = cvtpk(r0[it].x, r0[it].y); d[1] = cvtpk(r0[it].z, r0[it].w);
        }
        #pragma unroll
        for (int it = 0; it < 2; ++it) {
            int u = tid + it * 128;
            int nbr = u >> 4, c4 = u & 15;
            uint32* d = (uint32*)&fhat[(16 + nbr) * KS + 76 + c4 * 4];
            d[0] = cvtpk(r1[it].x, r1[it].y); d[1] = cvtpk(r1[it].z, r1[it].w);
        }
        if (tid < 32) ((uint32*)((char*)fhat + tid * 336))[5] = 0u;   // cols 10,11
        #pragma unroll
        for (int it = 0; it < 4; ++it) {                               // cols 140..167
            int u = tid + it * 128;
            if (u < 448) {
                int row = u / 14, jj = u - row * 14;
                ((uint32*)((char*)fhat + row * 336))[70 + jj] = 0u;
            }
        }
    }
    if (tid < 32) {
        const int r = tid;
        const bool lb = r < 16;
        const int idx = lb ? nm_lb[bq * 16 + r] : nm_sc[bq * 16 + (r - 16)];
        const float* nb = lb ? (c_lb + ((size_t)b * Nd + idx) * 3)
                             : (c_sc + ((size_t)b * Qn + idx) * 3);
        const float qx = c_q[bq * 3 + 0], qy = c_q[bq * 3 + 1], qz = c_q[bq * 3 + 2];
        const float nx = nb[0], ny = nb[1], nz = nb[2];
        const float rx = qx - nx, ry = qy - ny, rz = qz - nz;
        const float dd = sqrtf(rx * rx + ry * ry + rz * rz);
        uint32* pw = (uint32*)&pxs[tid * PXS];
        pw[0] = cvtpk(dd, rx); pw[1] = cvtpk(ry, rz); pw[2] = cvtpk(qx, qy);
        pw[3] = cvtpk(qz, nx); pw[4] = cvtpk(ny, nz);
        #pragma unroll
        for (int z = 5; z < 16; ++z) pw[z] = 0u;
    }
    __syncthreads();

    const f32x4 zf = {0.f, 0.f, 0.f, 0.f};

    // ---- convs via MFMA (16x16x32 shape) ----
    {
        bfrag pa1 = *(const bfrag*)&pxs[(16 + lrow) * PXS + lgr * 8];
        if (h == 0) {
            bfrag pa0 = *(const bfrag*)&pxs[lrow * PXS + lgr * 8];
            f32x4 c = __builtin_amdgcn_mfma_f32_16x16x32_bf16(pa0, wcv[0], zf, 0, 0, 0);
            if (lrow < 10) {
                #pragma unroll
                for (int r = 0; r < 4; ++r)
                    fhat[(lgr * 4 + r) * KS + lrow] =
                        cvt1(fmaxf(c[r] * bnv[0].x + bnv[0].y, 0.f));
            }
            #pragma unroll
            for (int t = 1; t < 3; ++t) {
                f32x4 c2 = __builtin_amdgcn_mfma_f32_16x16x32_bf16(pa1, wcv[t], zf, 0, 0, 0);
                const int o  = (t - 1) * 16 + lrow;
                const int cp = (o < 10) ? o : o + 2;
                #pragma unroll
                for (int r = 0; r < 4; ++r)
                    fhat[(16 + lgr * 4 + r) * KS + cp] =
                        cvt1(fmaxf(c2[r] * bnv[t].x + bnv[t].y, 0.f));
            }
        } else {
            #pragma unroll
            for (int t = 0; t < 3; ++t) {
                f32x4 c2 = __builtin_amdgcn_mfma_f32_16x16x32_bf16(pa1, wcv[t], zf, 0, 0, 0);
                const int o = (2 + t) * 16 + lrow;
                if (o < 74) {
                    #pragma unroll
                    for (int r = 0; r < 4; ++r)
                        fhat[(16 + lgr * 4 + r) * KS + o + 2] =
                            cvt1(fmaxf(c2[r] * bnv[t].x + bnv[t].y, 0.f));
                }
            }
        }
    }
    __syncthreads();

    // ---- att via 32x32x16: A frags once; h=0 -> nt{0,1,2}, h=1 -> nt{3,4} ----
    bfrag af32[10];
    #pragma unroll
    for (int kt = 0; kt < 10; ++kt)
        af32[kt] = *(const bfrag*)&fhat[(lane & 31) * KS + kt * 16 + ((lane >> 5) << 3)];
    const u16* frh = fhat + (lane >> 5) * 4 * KS;   // row = brow + 4*hi

    if (h == 0) {
        unit32(0, af32, W32, lane, frh, ag);
        unit32(1, af32, W32, lane, frh, ag);
        unit32(2, af32, W32, lane, frh, ag);
        if (lane < 2) ag[10 + lane] = 0;
    } else {
        unit32(3, af32, W32, lane, frh, ag);
        unit32(4, af32, W32, lane, frh, ag);
    }
}

// ---------------- mlp1: M=16 queries per wave-tile ----------------
__global__ __launch_bounds__(256) void mlp1(const u16* __restrict__ ws16,
                                            u16* __restrict__ ws16w)
{
    const int tid  = threadIdx.x;
    const int lane = tid & 63;
    const int w    = tid >> 6;
    const int lrow = lane & 15;
    const int lgr  = lane >> 4;
    const int q0   = (blockIdx.x * 4 + w) * 16;

    const u16* Wm = ws16 + OFF_WM1;
    const float* bn = (const float*)(ws16 + END_W);
    const u16* agg = ws16 + OFF_AG;
    u16* ftg = ws16w + OFF_FT;

    bfrag af[5];
    #pragma unroll
    for (int kt = 0; kt < 5; ++kt)
        af[kt] = *(const bfrag*)&agg[(size_t)(q0 + lrow) * AGS + kt * 32 + lgr * 8];

    const f32x4 zf = {0.f, 0.f, 0.f, 0.f};
    #pragma unroll
    for (int ot = 0; ot < 8; ++ot) {
        bfrag bf[5];
        loadB(bf, Wm, ot, lane);
        f32x4 c = zf;
        #pragma unroll
        for (int kt = 0; kt < 5; ++kt)
            c = __builtin_amdgcn_mfma_f32_16x16x32_bf16(af[kt], bf[kt], c, 0, 0, 0);
        const int o = ot * 16 + lrow;
        float2 p = *(const float2*)&bn[BN_M1 + o * 2];
        #pragma unroll
        for (int r = 0; r < 4; ++r) {
            int q = q0 + lgr * 4 + r;
            ftg[(size_t)q * 128 + o] = cvt1(fmaxf(c[r] * p.x + p.y, 0.f));
        }
    }
}

// ---------------- Stage 2 (fused, R12): 8 queries/block, 8 waves ----------------
__global__ __launch_bounds__(512, 4) void stage2(
    const int* __restrict__ nm_cl, const float* __restrict__ c_q,
    const u16* __restrict__ ws16, float* __restrict__ out)
{
    __shared__ __align__(16) u16 fhat[128 * KS];     // 43008 B
    __shared__ __align__(16) u16 pxs[128 * PXS];
    u16* aggs = pxs;

    const int tid  = threadIdx.x;
    const int bq0  = blockIdx.x * 8;
    const int b    = bq0 >> 14;
    const int q0   = bq0 & (Qn - 1);
    const int lane = tid & 63;
    const int w    = tid >> 6;               // 0..7 = my query
    const int lrow = lane & 15;
    const int lgr  = lane >> 4;

    const u16* W2t  = ws16 + OFF_W2;
    const u16* Wm2t = ws16 + OFF_WM2;
    const float* bn = (const float*)(ws16 + END_W);
    const u16* ft   = ws16 + OFF_FT;

    bfrag wcl = *(const bfrag*)&ws16[OFF_WCL + (lane << 3)];
    float2 bncl = (lrow < 10) ? *(const float2*)&bn[BN_CL + lrow * 2] : float2{0.f, 0.f};

    for (int u = tid; u < 128 * 15; u += 512) {       // zero cols 10,11 and 140..167
        int row = u / 15, jj = u - row * 15;
        uint32* base = (uint32*)((char*)fhat + row * 336);
        if (jj == 0) base[5] = 0u; else base[69 + jj] = 0u;
    }
    if (tid < 128) {
        const int qq = tid >> 4, r = tid & 15;
        const int bq = bq0 + qq;
        const int idx = nm_cl[bq * 16 + r];
        const float* nb = c_q + ((size_t)(b << 14) + idx) * 3;
        const float qx = c_q[bq * 3 + 0], qy = c_q[bq * 3 + 1], qz = c_q[bq * 3 + 2];
        const float nx = nb[0], ny = nb[1], nz = nb[2];
        const float rx = qx - nx, ry = qy - ny, rz = qz - nz;
        const float dd = sqrtf(rx * rx + ry * ry + rz * rz);
        uint32* pw = (uint32*)&pxs[tid * PXS];
        pw[0] = cvtpk(dd, rx); pw[1] = cvtpk(ry, rz); pw[2] = cvtpk(qx, qy);
        pw[3] = cvtpk(qz, nx); pw[4] = cvtpk(ny, nz);
        #pragma unroll
        for (int z = 5; z < 16; ++z) pw[z] = 0u;
    }
    #pragma unroll
    for (int i = 0; i < 16; ++i) {                    // gather f_tilde
        int u = tid + i * 512;
        int row = u >> 6, c2 = u & 63;
        int qq = row >> 4;
        int idx = nm_cl[(bq0 + qq) * 16 + (row & 15)];
        const uint32* srow = (const uint32*)(ft + (size_t)((b << 14) + idx) * 128);
        *(uint32*)&fhat[row * KS + 12 + c2 * 2] = srow[c2];
    }
    __syncthreads();

    const f32x4 zf = {0.f, 0.f, 0.f, 0.f};

    {
        bfrag pa = *(const bfrag*)&pxs[(w * 16 + lrow) * PXS + lgr * 8];
        f32x4 c = __builtin_amdgcn_mfma_f32_16x16x32_bf16(pa, wcl, zf, 0, 0, 0);
        if (lrow < 10) {
            #pragma unroll
            for (int r = 0; r < 4; ++r)
                fhat[(w * 16 + lgr * 4 + r) * KS + lrow] =
                    cvt1(fmaxf(c[r] * bncl.x + bncl.y, 0.f));
        }
    }
    __syncthreads();

    bfrag af[5];
    #pragma unroll
    for (int kt = 0; kt < 5; ++kt)
        af[kt] = *(const bfrag*)&fhat[(w * 16 + lrow) * KS + kt * 32 + lgr * 8];

    const u16* fr0 = fhat + (w * 16 + lgr * 4) * KS;
    u16* ag = aggs + w * AGS;

    bfrag b0[5], b1[5];
    f32x4 a0;
    loadB(b0, W2t, 0, lane);
    loadB(b1, W2t, 1, lane); mfma16(af, b0, a0); SB(); soft16(a0, 0, lane, lrow, fr0, ag);
    loadB(b0, W2t, 2, lane); mfma16(af, b1, a0); SB(); soft16(a0, 1, lane, lrow, fr0, ag);
    loadB(b1, W2t, 3, lane); mfma16(af, b0, a0); SB(); soft16(a0, 2, lane, lrow, fr0, ag);
    loadB(b0, W2t, 4, lane); mfma16(af, b1, a0); SB(); soft16(a0, 3, lane, lrow, fr0, ag);
    loadB(b1, W2t, 5, lane); mfma16(af, b0, a0); SB(); soft16(a0, 4, lane, lrow, fr0, ag);
    loadB(b0, W2t, 6, lane); mfma16(af, b1, a0); SB(); soft16(a0, 5, lane, lrow, fr0, ag);
    loadB(b1, W2t, 7, lane); mfma16(af, b0, a0); SB(); soft16(a0, 6, lane, lrow, fr0, ag);
    loadB(b0, W2t, 8, lane); mfma16(af, b1, a0); SB(); soft16(a0, 7, lane, lrow, fr0, ag);
    mfma16(af, b0, a0); soft16(a0, 8, lane, lrow, fr0, ag);
    if (lane < 2)       ag[10 + lane] = 0;
    else if (lane < 16) ag[144 + lane] = 0;
    __syncthreads();

    bfrag am[5];
    #pragma unroll
    for (int kt = 0; kt < 5; ++kt)
        am[kt] = *(const bfrag*)&aggs[lrow * AGS + kt * 32 + lgr * 8];
    {
        f32x4 c = zf;
        #pragma unroll
        for (int kt = 0; kt < 5; ++kt) {
            bfrag wm = *(const bfrag*)&Wm2t[(((w * 5) + kt) << 9) + (lane << 3)];
            c = __builtin_amdgcn_mfma_f32_16x16x32_bf16(am[kt], wm, c, 0, 0, 0);
        }
        if (lgr < 2) {
            const int o = w * 16 + lrow;
            float2 p = *(const float2*)&bn[BN_M2 + o * 2];
            #pragma unroll
            for (int r = 0; r < 4; ++r) {
                const int qloc = lgr * 4 + r;
                out[((size_t)(b * 128 + o) << 14) + q0 + qloc] = fmaxf(c[r] * p.x + p.y, 0.f);
            }
        }
    }
}

extern "C" void kernel_launch(void* const* d_in, const int* in_sizes, int n_in,
                              void* d_out, int out_size, void* d_ws, size_t ws_size,
                              hipStream_t stream)
{
    const float* feat_lb = (const float*)d_in[0];
    const float* feat_sc = (const float*)d_in[1];
    const int*   nm_lb   = (const int*)d_in[2];
    const int*   nm_sc   = (const int*)d_in[3];
    const float* c_lb    = (const float*)d_in[4];
    const float* c_sc    = (const float*)d_in[5];
    const float* c_q     = (const float*)d_in[6];
    const int*   nm_cl   = (const int*)d_in[7];
    const float* W_lb = (const float*)d_in[8];
    const float* g_lb = (const float*)d_in[9];
    const float* b_lb = (const float*)d_in[10];
    const float* m_lb = (const float*)d_in[11];
    const float* v_lb = (const float*)d_in[12];
    const float* W_sc = (const float*)d_in[13];
    const float* g_sc = (const float*)d_in[14];
    const float* b_sc = (const float*)d_in[15];
    const float* m_sc = (const float*)d_in[16];
    const float* v_sc = (const float*)d_in[17];
    const float* W_fc1  = (const float*)d_in[18];
    const float* W_mlp1 = (const float*)d_in[19];
    const float* g1 = (const float*)d_in[20];
    const float* b1 = (const float*)d_in[21];
    const float* m1 = (const float*)d_in[22];
    const float* v1 = (const float*)d_in[23];
    const float* W_cl = (const float*)d_in[24];
    const float* g_cl = (const float*)d_in[25];
    const float* b_cl = (const float*)d_in[26];
    const float* m_cl = (const float*)d_in[27];
    const float* v_cl = (const float*)d_in[28];
    const float* W_fc2  = (const float*)d_in[29];
    const float* W_mlp2 = (const float*)d_in[30];
    const float* g2 = (const float*)d_in[31];
    const float* b2 = (const float*)d_in[32];
    const float* m2 = (const float*)d_in[33];
    const float* v2 = (const float*)d_in[34];

    u16* ws16 = (u16*)d_ws;
    float* out = (float*)d_out;

    hipLaunchKernelGGL(prep_weights, dim3((PREP_N + 255) / 256), dim3(256), 0, stream,
        W_fc1, W_mlp1, W_fc2, W_mlp2, W_lb, W_sc, W_cl,
        g_lb, b_lb, m_lb, v_lb, g_sc, b_sc, m_sc, v_sc,
        g_cl, b_cl, m_cl, v_cl, g1, b1, m1, v1, g2, b2, m2, v2, ws16);

    hipLaunchKernelGGL(prep_weights32, dim3((N_W32 + 255) / 256), dim3(256), 0, stream,
        W_fc1, W_fc2, ws16);

    hipLaunchKernelGGL(stage1, dim3(2 * Qn), dim3(128), 0, stream,
        feat_lb, feat_sc, nm_lb, nm_sc, c_lb, c_sc, c_q, ws16);

    hipLaunchKernelGGL(mlp1, dim3(2 * Qn / 64), dim3(256), 0, stream, ws16, ws16);

    hipLaunchKernelGGL(stage2, dim3(2 * Qn / 8), dim3(512), 0, stream,
        nm_cl, c_q, ws16, out);
}

// Round 15
// 219.668 us; speedup vs baseline: 1.0441x; 1.0441x over previous
//
#include <hip/hip_runtime.h>
#include <cmath>

#define EPSF 1e-5f
typedef unsigned int  uint32;
typedef unsigned short u16;
typedef __attribute__((ext_vector_type(8))) short bfrag;   // 8 bf16 = 4 VGPRs
typedef __attribute__((ext_vector_type(4))) float f32x4;

constexpr int Qn   = 16384;
constexpr int KS   = 168;    // fhat K stride (bf16) = 336 B
constexpr int PXS  = 42;     // px stride (u16)
constexpr int AGS  = 168;    // agg row stride (u16)
constexpr int Nd   = 4096;
constexpr float LOG2E = 1.4426950408889634f;

constexpr int OFF_W1  = 0;                 // W_fc1 (xLOG2E) 9x5x512
constexpr int OFF_WM1 = 23040;             // W_mlp1 8x5x512
constexpr int OFF_W2  = 43520;             // W_fc2 (xLOG2E)
constexpr int OFF_WM2 = 66560;             // W_mlp2
constexpr int OFF_WLB = 87040;
constexpr int OFF_WSC = 87552;
constexpr int OFF_WCL = 90112;
constexpr int END_W   = 90624;
constexpr int BN_LB = 0;
constexpr int BN_SC = 20;
constexpr int BN_CL = 168;
constexpr int BN_M1 = 188;
constexpr int BN_M2 = 444;
constexpr int BN_TOT = 700;
constexpr int OFF_FT  = END_W + 2 * BN_TOT;                 // u16: 2Q x 128
constexpr int OFF_AG  = OFF_FT + 2 * Qn * 128;              // u16: 2Q x 168
constexpr int PREP_N  = END_W + BN_TOT;

__device__ __forceinline__ u16 f2b(float f) {
    uint32 u = __float_as_uint(f);
    uint32 r = (u + 0x7fffu + ((u >> 16) & 1u)) >> 16;
    return (u16)r;
}
__device__ __forceinline__ float b2f(u16 h) {
    return __uint_as_float(((uint32)h) << 16);
}
__device__ __forceinline__ uint32 cvtpk(float a, float b) {
    uint32 r;
    asm("v_cvt_pk_bf16_f32 %0, %1, %2" : "=v"(r) : "v"(a), "v"(b));
    return r;
}
__device__ __forceinline__ u16 cvt1(float a) { return (u16)cvtpk(a, a); }
__device__ __forceinline__ float exp2_hw(float x) { return __builtin_amdgcn_exp2f(x); }

// ---------------- weight pre-conversion + BN pair precompute ----------------
__global__ __launch_bounds__(256) void prep_weights(
    const float* __restrict__ Wfc1, const float* __restrict__ Wmlp1,
    const float* __restrict__ Wfc2, const float* __restrict__ Wmlp2,
    const float* __restrict__ Wlb,  const float* __restrict__ Wsc,
    const float* __restrict__ Wcl,
    const float* __restrict__ g_lb, const float* __restrict__ b_lb,
    const float* __restrict__ m_lb, const float* __restrict__ v_lb,
    const float* __restrict__ g_sc, const float* __restrict__ b_sc,
    const float* __restrict__ m_sc, const float* __restrict__ v_sc,
    const float* __restrict__ g_cl, const float* __restrict__ b_cl,
    const float* __restrict__ m_cl, const float* __restrict__ v_cl,
    const float* __restrict__ g1, const float* __restrict__ b1,
    const float* __restrict__ m1, const float* __restrict__ v1,
    const float* __restrict__ g2, const float* __restrict__ b2,
    const float* __restrict__ m2, const float* __restrict__ v2,
    u16* __restrict__ ws16)
{
    int i = blockIdx.x * 256 + threadIdx.x;
    if (i >= PREP_N) return;
    if (i >= END_W) {                      // BN pairs
        int j = i - END_W;
        const float *g, *bb, *m, *v; int o2;
        if (j < BN_SC)      { g = g_lb; bb = b_lb; m = m_lb; v = v_lb; o2 = j - BN_LB; }
        else if (j < BN_CL) { g = g_sc; bb = b_sc; m = m_sc; v = v_sc; o2 = j - BN_SC; }
        else if (j < BN_M1) { g = g_cl; bb = b_cl; m = m_cl; v = v_cl; o2 = j - BN_CL; }
        else if (j < BN_M2) { g = g1;   bb = b1;   m = m1;   v = v1;   o2 = j - BN_M1; }
        else                { g = g2;   bb = b2;   m = m2;   v = v2;   o2 = j - BN_M2; }
        int o = o2 >> 1;
        float sc_ = g[o] * rsqrtf(v[o] + EPSF);
        ((float*)(ws16 + END_W))[j] = (o2 & 1) ? (bb[o] - m[o] * sc_) : sc_;
        return;
    }
    int lane = (i >> 3) & 63, jj = i & 7;
    int row16 = lane & 15;
    int kf = ((lane >> 4) << 3) + jj;
    float v = 0.f;
    if (i < OFF_WLB) {                    // att / mlp weights, K remapped
        const float* src; int nrows; int idx; bool fc = false;
        if (i < OFF_WM1)      { src = Wfc1;  nrows = 138; idx = i - OFF_W1;  fc = true; }
        else if (i < OFF_W2)  { src = Wmlp1; nrows = 128; idx = i - OFF_WM1; }
        else if (i < OFF_WM2) { src = Wfc2;  nrows = 138; idx = i - OFF_W2;  fc = true; }
        else                  { src = Wmlp2; nrows = 128; idx = i - OFF_WM2; }
        int t = idx >> 9, nt = t / 5, kt = t - nt * 5;
        int row = nt * 16 + row16;
        int kp  = kt * 32 + kf;
        int k   = (kp < 10) ? kp : kp - 2;
        if (row < nrows && kp < 140 && kp != 10 && kp != 11) {
            v = src[row * 138 + k];
            if (fc) v *= LOG2E;
        }
    } else {                              // conv weights, K = 10 (pad 32)
        const float* src; int nrows; int idx;
        if (i < OFF_WSC)      { src = Wlb; nrows = 10; idx = i - OFF_WLB; }
        else if (i < OFF_WCL) { src = Wsc; nrows = 74; idx = i - OFF_WSC; }
        else                  { src = Wcl; nrows = 10; idx = i - OFF_WCL; }
        int t = idx >> 9;
        int row = t * 16 + row16;
        if (row < nrows && kf < 10) v = src[row * 10 + kf];
    }
    ws16[i] = f2b(v);
}

// ---- helpers ----
__device__ __forceinline__ void loadB(bfrag (&bf)[5], const u16* __restrict__ Wt,
                                      int nt, int lane) {
    #pragma unroll
    for (int kt = 0; kt < 5; ++kt)
        bf[kt] = *(const bfrag*)&Wt[((nt * 5 + kt) << 9) + (lane << 3)];
}
__device__ __forceinline__ void mfma32(const bfrag (&af)[2][5], const bfrag (&bf)[5],
                                       f32x4 &a0, f32x4 &a1) {
    const f32x4 zf = {0.f, 0.f, 0.f, 0.f};
    a0 = zf; a1 = zf;
    #pragma unroll
    for (int kt = 0; kt < 5; ++kt) {
        a0 = __builtin_amdgcn_mfma_f32_16x16x32_bf16(af[0][kt], bf[kt], a0, 0, 0, 0);
        a1 = __builtin_amdgcn_mfma_f32_16x16x32_bf16(af[1][kt], bf[kt], a1, 0, 0, 0);
    }
}
__device__ __forceinline__ void mfma16(const bfrag (&af)[5], const bfrag (&bf)[5],
                                       f32x4 &a0) {
    const f32x4 zf = {0.f, 0.f, 0.f, 0.f};
    a0 = zf;
    #pragma unroll
    for (int kt = 0; kt < 5; ++kt)
        a0 = __builtin_amdgcn_mfma_f32_16x16x32_bf16(af[kt], bf[kt], a0, 0, 0, 0);
}
// softmax over 32 rows; ag may be global or LDS
__device__ __forceinline__ void soft32(
    const f32x4& a0, const f32x4& a1, int nt,
    int lane, int lrow, const u16* __restrict__ fr0, const u16* __restrict__ fr1,
    u16* __restrict__ ag)
{
    const int ch  = nt * 16 + lrow;
    const int chp = ch + (ch >= 10 ? 2 : 0);
    float s = 0.f, num = 0.f;
    #pragma unroll
    for (int r = 0; r < 4; ++r) {
        float e = exp2_hw(a0[r]);
        s += e;
        num += e * b2f(fr0[r * KS + chp]);
    }
    #pragma unroll
    for (int r = 0; r < 4; ++r) {
        float e = exp2_hw(a1[r]);
        s += e;
        num += e * b2f(fr1[r * KS + chp]);
    }
    s   += __shfl_xor(s, 16);   s   += __shfl_xor(s, 32);
    num += __shfl_xor(num, 16); num += __shfl_xor(num, 32);
    if (lane < 16)
        ag[chp] = cvt1((ch < 138) ? num * __builtin_amdgcn_rcpf(s) : 0.f);
}
__device__ __forceinline__ void soft16(
    const f32x4& a0, int nt,
    int lane, int lrow, const u16* __restrict__ fr0, u16* __restrict__ ag)
{
    const int ch  = nt * 16 + lrow;
    const int chp = ch + (ch >= 10 ? 2 : 0);
    float s = 0.f, num = 0.f;
    #pragma unroll
    for (int r = 0; r < 4; ++r) {
        float e = exp2_hw(a0[r]);
        s += e;
        num += e * b2f(fr0[r * KS + chp]);
    }
    s   += __shfl_xor(s, 16);   s   += __shfl_xor(s, 32);
    num += __shfl_xor(num, 16); num += __shfl_xor(num, 32);
    if (lane < 16)
        ag[chp] = cvt1((ch < 138) ? num * __builtin_amdgcn_rcpf(s) : 0.f);
}
#define SB() __builtin_amdgcn_sched_barrier(0)

// ---------------- Stage 1 (R13 best): 1 query/block, 2 waves ----------------
__global__ __launch_bounds__(128, 8) void stage1(
    const float* __restrict__ feat_lb, const float* __restrict__ feat_sc,
    const int* __restrict__ nm_lb, const int* __restrict__ nm_sc,
    const float* __restrict__ c_lb, const float* __restrict__ c_sc,
    const float* __restrict__ c_q,
    u16* __restrict__ ws16)
{
    __shared__ __align__(16) u16 fhat[32 * KS];      // 10752 B
    __shared__ __align__(16) u16 pxs[32 * PXS];      // 2688 B

    const int tid  = threadIdx.x;
    const int bq   = blockIdx.x;             // one query
    const int b    = bq >> 14;
    const int lane = tid & 63;
    const int h    = tid >> 6;               // 0..1 = nt-half
    const int lrow = lane & 15;
    const int lgr  = lane >> 4;

    const u16* W1t  = ws16 + OFF_W1;
    const float* bn = (const float*)(ws16 + END_W);
    u16* ag = ws16 + OFF_AG + (size_t)bq * AGS;

    // ---- conv weights + BN for my subset ----
    bfrag wcv[3];
    float2 bnv[3];
    if (h == 0) {
        wcv[0] = *(const bfrag*)&ws16[OFF_WLB + (lane << 3)];
        wcv[1] = *(const bfrag*)&ws16[OFF_WSC + (lane << 3)];
        wcv[2] = *(const bfrag*)&ws16[OFF_WSC + 512 + (lane << 3)];
        bnv[0] = (lrow < 10) ? *(const float2*)&bn[BN_LB + lrow * 2] : float2{0.f, 0.f};
        bnv[1] = *(const float2*)&bn[BN_SC + lrow * 2];
        bnv[2] = *(const float2*)&bn[BN_SC + (16 + lrow) * 2];
    } else {
        #pragma unroll
        for (int t = 0; t < 3; ++t) {
            wcv[t] = *(const bfrag*)&ws16[OFF_WSC + ((2 + t) << 9) + (lane << 3)];
            int o = (2 + t) * 16 + lrow;
            bnv[t] = (o < 74) ? *(const float2*)&bn[BN_SC + o * 2] : float2{0.f, 0.f};
        }
    }

    // ---- staging: features -> fhat (bf16), zero pads, px ----
    {
        const float4* flb = (const float4*)(feat_lb + (size_t)bq * 2048);
        float4 r0[4];
        #pragma unroll
        for (int it = 0; it < 4; ++it) r0[it] = flb[tid + it * 128];
        const float4* fsc = (const float4*)(feat_sc + (size_t)bq * 1024);
        float4 r1[2];
        #pragma unroll
        for (int it = 0; it < 2; ++it) r1[it] = fsc[tid + it * 128];
        #pragma unroll
        for (int it = 0; it < 4; ++it) {
            int u = tid + it * 128;
            int nbr = u >> 5, c4 = u & 31;
            uint32* d = (uint32*)&fhat[nbr * KS + 12 + c4 * 4];
            d[0] = cvtpk(r0[it].x, r0[it].y); d[1] = cvtpk(r0[it].z, r0[it].w);
        }
        #pragma unroll
        for (int it = 0; it < 2; ++it) {
            int u = tid + it * 128;
            int nbr = u >> 4, c4 = u & 15;
            uint32* d = (uint32*)&fhat[(16 + nbr) * KS + 76 + c4 * 4];
            d[0] = cvtpk(r1[it].x, r1[it].y); d[1] = cvtpk(r1[it].z, r1[it].w);
        }
        if (tid < 32) ((uint32*)((char*)fhat + tid * 336))[5] = 0u;   // cols 10,11
        #pragma unroll
        for (int it = 0; it < 4; ++it) {                               // cols 140..167
            int u = tid + it * 128;
            if (u < 448) {
                int row = u / 14, jj = u - row * 14;
                ((uint32*)((char*)fhat + row * 336))[70 + jj] = 0u;
            }
        }
    }
    if (tid < 32) {
        const int r = tid;
        const bool lb = r < 16;
        const int idx = lb ? nm_lb[bq * 16 + r] : nm_sc[bq * 16 + (r - 16)];
        const float* nb = lb ? (c_lb + ((size_t)b * Nd + idx) * 3)
                             : (c_sc + ((size_t)b * Qn + idx) * 3);
        const float qx = c_q[bq * 3 + 0], qy = c_q[bq * 3 + 1], qz = c_q[bq * 3 + 2];
        const float nx = nb[0], ny = nb[1], nz = nb[2];
        const float rx = qx - nx, ry = qy - ny, rz = qz - nz;
        const float dd = sqrtf(rx * rx + ry * ry + rz * rz);
        uint32* pw = (uint32*)&pxs[tid * PXS];
        pw[0] = cvtpk(dd, rx); pw[1] = cvtpk(ry, rz); pw[2] = cvtpk(qx, qy);
        pw[3] = cvtpk(qz, nx); pw[4] = cvtpk(ny, nz);
        #pragma unroll
        for (int z = 5; z < 16; ++z) pw[z] = 0u;
    }
    __syncthreads();

    const f32x4 zf = {0.f, 0.f, 0.f, 0.f};

    // ---- convs via MFMA ----
    {
        bfrag pa1 = *(const bfrag*)&pxs[(16 + lrow) * PXS + lgr * 8];
        if (h == 0) {
            bfrag pa0 = *(const bfrag*)&pxs[lrow * PXS + lgr * 8];
            f32x4 c = __builtin_amdgcn_mfma_f32_16x16x32_bf16(pa0, wcv[0], zf, 0, 0, 0);
            if (lrow < 10) {
                #pragma unroll
                for (int r = 0; r < 4; ++r)
                    fhat[(lgr * 4 + r) * KS + lrow] =
                        cvt1(fmaxf(c[r] * bnv[0].x + bnv[0].y, 0.f));
            }
            #pragma unroll
            for (int t = 1; t < 3; ++t) {
                f32x4 c2 = __builtin_amdgcn_mfma_f32_16x16x32_bf16(pa1, wcv[t], zf, 0, 0, 0);
                const int o  = (t - 1) * 16 + lrow;
                const int cp = (o < 10) ? o : o + 2;
                #pragma unroll
                for (int r = 0; r < 4; ++r)
                    fhat[(16 + lgr * 4 + r) * KS + cp] =
                        cvt1(fmaxf(c2[r] * bnv[t].x + bnv[t].y, 0.f));
            }
        } else {
            #pragma unroll
            for (int t = 0; t < 3; ++t) {
                f32x4 c2 = __builtin_amdgcn_mfma_f32_16x16x32_bf16(pa1, wcv[t], zf, 0, 0, 0);
                const int o = (2 + t) * 16 + lrow;
                if (o < 74) {
                    #pragma unroll
                    for (int r = 0; r < 4; ++r)
                        fhat[(16 + lgr * 4 + r) * KS + o + 2] =
                            cvt1(fmaxf(c2[r] * bnv[t].x + bnv[t].y, 0.f));
                }
            }
        }
    }
    __syncthreads();

    // ---- att: af once in regs; B pipelined b0/b1 ----
    bfrag af[2][5];
    #pragma unroll
    for (int mt = 0; mt < 2; ++mt)
        #pragma unroll
        for (int kt = 0; kt < 5; ++kt)
            af[mt][kt] = *(const bfrag*)&fhat[(mt * 16 + lrow) * KS + kt * 32 + lgr * 8];

    const u16* fr0 = fhat + (lgr * 4) * KS;
    const u16* fr1 = fr0 + 16 * KS;

    bfrag b0[5], b1[5];
    f32x4 a0, a1;
    if (h == 0) {
        loadB(b0, W1t, 0, lane);
        loadB(b1, W1t, 1, lane); mfma32(af, b0, a0, a1); SB(); soft32(a0, a1, 0, lane, lrow, fr0, fr1, ag);
        loadB(b0, W1t, 2, lane); mfma32(af, b1, a0, a1); SB(); soft32(a0, a1, 1, lane, lrow, fr0, fr1, ag);
        loadB(b1, W1t, 3, lane); mfma32(af, b0, a0, a1); SB(); soft32(a0, a1, 2, lane, lrow, fr0, fr1, ag);
        loadB(b0, W1t, 4, lane); mfma32(af, b1, a0, a1); SB(); soft32(a0, a1, 3, lane, lrow, fr0, fr1, ag);
        mfma32(af, b0, a0, a1); soft32(a0, a1, 4, lane, lrow, fr0, fr1, ag);
        if (lane < 2)       ag[10 + lane] = 0;
        else if (lane < 16) ag[144 + lane] = 0;
    } else {
        loadB(b0, W1t, 5, lane);
        loadB(b1, W1t, 6, lane); mfma32(af, b0, a0, a1); SB(); soft32(a0, a1, 5, lane, lrow, fr0, fr1, ag);
        loadB(b0, W1t, 7, lane); mfma32(af, b1, a0, a1); SB(); soft32(a0, a1, 6, lane, lrow, fr0, fr1, ag);
        loadB(b1, W1t, 8, lane); mfma32(af, b0, a0, a1); SB(); soft32(a0, a1, 7, lane, lrow, fr0, fr1, ag);
        mfma32(af, b1, a0, a1); soft32(a0, a1, 8, lane, lrow, fr0, fr1, ag);
    }
}

// ---------------- mlp1: M=16 queries per wave-tile ----------------
__global__ __launch_bounds__(256) void mlp1(const u16* __restrict__ ws16,
                                            u16* __restrict__ ws16w)
{
    const int tid  = threadIdx.x;
    const int lane = tid & 63;
    const int w    = tid >> 6;
    const int lrow = lane & 15;
    const int lgr  = lane >> 4;
    const int q0   = (blockIdx.x * 4 + w) * 16;

    const u16* Wm = ws16 + OFF_WM1;
    const float* bn = (const float*)(ws16 + END_W);
    const u16* agg = ws16 + OFF_AG;
    u16* ftg = ws16w + OFF_FT;

    bfrag af[5];
    #pragma unroll
    for (int kt = 0; kt < 5; ++kt)
        af[kt] = *(const bfrag*)&agg[(size_t)(q0 + lrow) * AGS + kt * 32 + lgr * 8];

    const f32x4 zf = {0.f, 0.f, 0.f, 0.f};
    #pragma unroll
    for (int ot = 0; ot < 8; ++ot) {
        bfrag bf[5];
        loadB(bf, Wm, ot, lane);
        f32x4 c = zf;
        #pragma unroll
        for (int kt = 0; kt < 5; ++kt)
            c = __builtin_amdgcn_mfma_f32_16x16x32_bf16(af[kt], bf[kt], c, 0, 0, 0);
        const int o = ot * 16 + lrow;
        float2 p = *(const float2*)&bn[BN_M1 + o * 2];
        #pragma unroll
        for (int r = 0; r < 4; ++r) {
            int q = q0 + lgr * 4 + r;
            ftg[(size_t)q * 128 + o] = cvt1(fmaxf(c[r] * p.x + p.y, 0.f));
        }
    }
}

// ---------------- Stage 2 (R12 fused): 8 queries/block, 8 waves ----------------
__global__ __launch_bounds__(512, 4) void stage2(
    const int* __restrict__ nm_cl, const float* __restrict__ c_q,
    const u16* __restrict__ ws16, float* __restrict__ out)
{
    __shared__ __align__(16) u16 fhat[128 * KS];     // 43008 B
    __shared__ __align__(16) u16 pxs[128 * PXS];
    u16* aggs = pxs;

    const int tid  = threadIdx.x;
    const int bq0  = blockIdx.x * 8;
    const int b    = bq0 >> 14;
    const int q0   = bq0 & (Qn - 1);
    const int lane = tid & 63;
    const int w    = tid >> 6;               // 0..7 = my query
    const int lrow = lane & 15;
    const int lgr  = lane >> 4;

    const u16* W2t  = ws16 + OFF_W2;
    const u16* Wm2t = ws16 + OFF_WM2;
    const float* bn = (const float*)(ws16 + END_W);
    const u16* ft   = ws16 + OFF_FT;

    bfrag wcl = *(const bfrag*)&ws16[OFF_WCL + (lane << 3)];
    float2 bncl = (lrow < 10) ? *(const float2*)&bn[BN_CL + lrow * 2] : float2{0.f, 0.f};

    for (int u = tid; u < 128 * 15; u += 512) {       // zero cols 10,11 and 140..167
        int row = u / 15, jj = u - row * 15;
        uint32* base = (uint32*)((char*)fhat + row * 336);
        if (jj == 0) base[5] = 0u; else base[69 + jj] = 0u;
    }
    if (tid < 128) {
        const int qq = tid >> 4, r = tid & 15;
        const int bq = bq0 + qq;
        const int idx = nm_cl[bq * 16 + r];
        const float* nb = c_q + ((size_t)(b << 14) + idx) * 3;
        const float qx = c_q[bq * 3 + 0], qy = c_q[bq * 3 + 1], qz = c_q[bq * 3 + 2];
        const float nx = nb[0], ny = nb[1], nz = nb[2];
        const float rx = qx - nx, ry = qy - ny, rz = qz - nz;
        const float dd = sqrtf(rx * rx + ry * ry + rz * rz);
        uint32* pw = (uint32*)&pxs[tid * PXS];
        pw[0] = cvtpk(dd, rx); pw[1] = cvtpk(ry, rz); pw[2] = cvtpk(qx, qy);
        pw[3] = cvtpk(qz, nx); pw[4] = cvtpk(ny, nz);
        #pragma unroll
        for (int z = 5; z < 16; ++z) pw[z] = 0u;
    }
    #pragma unroll
    for (int i = 0; i < 16; ++i) {                    // gather f_tilde
        int u = tid + i * 512;
        int row = u >> 6, c2 = u & 63;
        int qq = row >> 4;
        int idx = nm_cl[(bq0 + qq) * 16 + (row & 15)];
        const uint32* srow = (const uint32*)(ft + (size_t)((b << 14) + idx) * 128);
        *(uint32*)&fhat[row * KS + 12 + c2 * 2] = srow[c2];
    }
    __syncthreads();

    const f32x4 zf = {0.f, 0.f, 0.f, 0.f};

    {
        bfrag pa = *(const bfrag*)&pxs[(w * 16 + lrow) * PXS + lgr * 8];
        f32x4 c = __builtin_amdgcn_mfma_f32_16x16x32_bf16(pa, wcl, zf, 0, 0, 0);
        if (lrow < 10) {
            #pragma unroll
            for (int r = 0; r < 4; ++r)
                fhat[(w * 16 + lgr * 4 + r) * KS + lrow] =
                    cvt1(fmaxf(c[r] * bncl.x + bncl.y, 0.f));
        }
    }
    __syncthreads();

    bfrag af[5];
    #pragma unroll
    for (int kt = 0; kt < 5; ++kt)
        af[kt] = *(const bfrag*)&fhat[(w * 16 + lrow) * KS + kt * 32 + lgr * 8];

    const u16* fr0 = fhat + (w * 16 + lgr * 4) * KS;
    u16* ag = aggs + w * AGS;

    bfrag b0[5], b1[5];
    f32x4 a0;
    loadB(b0, W2t, 0, lane);
    loadB(b1, W2t, 1, lane); mfma16(af, b0, a0); SB(); soft16(a0, 0, lane, lrow, fr0, ag);
    loadB(b0, W2t, 2, lane); mfma16(af, b1, a0); SB(); soft16(a0, 1, lane, lrow, fr0, ag);
    loadB(b1, W2t, 3, lane); mfma16(af, b0, a0); SB(); soft16(a0, 2, lane, lrow, fr0, ag);
    loadB(b0, W2t, 4, lane); mfma16(af, b1, a0); SB(); soft16(a0, 3, lane, lrow, fr0, ag);
    loadB(b1, W2t, 5, lane); mfma16(af, b0, a0); SB(); soft16(a0, 4, lane, lrow, fr0, ag);
    loadB(b0, W2t, 6, lane); mfma16(af, b1, a0); SB(); soft16(a0, 5, lane, lrow, fr0, ag);
    loadB(b1, W2t, 7, lane); mfma16(af, b0, a0); SB(); soft16(a0, 6, lane, lrow, fr0, ag);
    loadB(b0, W2t, 8, lane); mfma16(af, b1, a0); SB(); soft16(a0, 7, lane, lrow, fr0, ag);
    mfma16(af, b0, a0); soft16(a0, 8, lane, lrow, fr0, ag);
    if (lane < 2)       ag[10 + lane] = 0;
    else if (lane < 16) ag[144 + lane] = 0;
    __syncthreads();

    bfrag am[5];
    #pragma unroll
    for (int kt = 0; kt < 5; ++kt)
        am[kt] = *(const bfrag*)&aggs[lrow * AGS + kt * 32 + lgr * 8];
    {
        f32x4 c = zf;
        #pragma unroll
        for (int kt = 0; kt < 5; ++kt) {
            bfrag wm = *(const bfrag*)&Wm2t[(((w * 5) + kt) << 9) + (lane << 3)];
            c = __builtin_amdgcn_mfma_f32_16x16x32_bf16(am[kt], wm, c, 0, 0, 0);
        }
        if (lgr < 2) {
            const int o = w * 16 + lrow;
            float2 p = *(const float2*)&bn[BN_M2 + o * 2];
            #pragma unroll
            for (int r = 0; r < 4; ++r) {
                const int qloc = lgr * 4 + r;
                out[((size_t)(b * 128 + o) << 14) + q0 + qloc] = fmaxf(c[r] * p.x + p.y, 0.f);
            }
        }
    }
}

extern "C" void kernel_launch(void* const* d_in, const int* in_sizes, int n_in,
                              void* d_out, int out_size, void* d_ws, size_t ws_size,
                              hipStream_t stream)
{
    const float* feat_lb = (const float*)d_in[0];
    const float* feat_sc = (const float*)d_in[1];
    const int*   nm_lb   = (const int*)d_in[2];
    const int*   nm_sc   = (const int*)d_in[3];
    const float* c_lb    = (const float*)d_in[4];
    const float* c_sc    = (const float*)d_in[5];
    const float* c_q     = (const float*)d_in[6];
    const int*   nm_cl   = (const int*)d_in[7];
    const float* W_lb = (const float*)d_in[8];
    const float* g_lb = (const float*)d_in[9];
    const float* b_lb = (const float*)d_in[10];
    const float* m_lb = (const float*)d_in[11];
    const float* v_lb = (const float*)d_in[12];
    const float* W_sc = (const float*)d_in[13];
    const float* g_sc = (const float*)d_in[14];
    const float* b_sc = (const float*)d_in[15];
    const float* m_sc = (const float*)d_in[16];
    const float* v_sc = (const float*)d_in[17];
    const float* W_fc1  = (const float*)d_in[18];
    const float* W_mlp1 = (const float*)d_in[19];
    const float* g1 = (const float*)d_in[20];
    const float* b1 = (const float*)d_in[21];
    const float* m1 = (const float*)d_in[22];
    const float* v1 = (const float*)d_in[23];
    const float* W_cl = (const float*)d_in[24];
    const float* g_cl = (const float*)d_in[25];
    const float* b_cl = (const float*)d_in[26];
    const float* m_cl = (const float*)d_in[27];
    const float* v_cl = (const float*)d_in[28];
    const float* W_fc2  = (const float*)d_in[29];
    const float* W_mlp2 = (const float*)d_in[30];
    const float* g2 = (const float*)d_in[31];
    const float* b2 = (const float*)d_in[32];
    const float* m2 = (const float*)d_in[33];
    const float* v2 = (const float*)d_in[34];

    u16* ws16 = (u16*)d_ws;
    float* out = (float*)d_out;

    hipLaunchKernelGGL(prep_weights, dim3((PREP_N + 255) / 256), dim3(256), 0, stream,
        W_fc1, W_mlp1, W_fc2, W_mlp2, W_lb, W_sc, W_cl,
        g_lb, b_lb, m_lb, v_lb, g_sc, b_sc, m_sc, v_sc,
        g_cl, b_cl, m_cl, v_cl, g1, b1, m1, v1, g2, b2, m2, v2, ws16);

    hipLaunchKernelGGL(stage1, dim3(2 * Qn), dim3(128), 0, stream,
        feat_lb, feat_sc, nm_lb, nm_sc, c_lb, c_sc, c_q, ws16);

    hipLaunchKernelGGL(mlp1, dim3(2 * Qn / 64), dim3(256), 0, stream, ws16, ws16);

    hipLaunchKernelGGL(stage2, dim3(2 * Qn / 8), dim3(512), 0, stream,
        nm_cl, c_q, ws16, out);
}